// Round 3
// baseline (7389.898 us; speedup 1.0000x reference)
//
#include <hip/hip_runtime.h>

#define B_   64
#define T_   512
#define DIN  300
#define H_   512
#define G3   1536   // 3*H
#define TWOH 1024
#define R_   256
#define KX   320    // DIN padded to mult of 32

typedef __attribute__((ext_vector_type(8))) short short8;
typedef __attribute__((ext_vector_type(4))) float f32x4;

__device__ __forceinline__ unsigned short f2bf(float f) {
  union { float f; unsigned int u; } v; v.f = f;
  unsigned int u = v.u;
  u += 0x7fffu + ((u >> 16) & 1u);   // RTN
  return (unsigned short)(u >> 16);
}
__device__ __forceinline__ float bf2f(unsigned short h) {
  union { unsigned int u; float f; } v; v.u = ((unsigned int)h) << 16;
  return v.f;
}
// device-coherent (cross-XCD) relaxed accesses — no cache-nuking fences
__device__ __forceinline__ unsigned int aload(const unsigned int* p) {
  return __hip_atomic_load((unsigned int*)p, __ATOMIC_RELAXED,
                           __HIP_MEMORY_SCOPE_AGENT);
}
__device__ __forceinline__ void astore(unsigned int* p, unsigned int v) {
  __hip_atomic_store(p, v, __ATOMIC_RELAXED, __HIP_MEMORY_SCOPE_AGENT);
}

// ---------------------------------------------------------------------------
// K0: X fp32 [B,T,300] -> Xbf bf16 [B,T,320] (zero-padded cols 300..319)
// ---------------------------------------------------------------------------
__global__ __launch_bounds__(256) void k_xbf(
    const float* __restrict__ X, unsigned short* __restrict__ Xbf)
{
  const int id = blockIdx.x * 256 + threadIdx.x;      // B*T*40 items
  if (id >= B_ * T_ * 40) return;
  const int row = id / 40, c = id % 40, k = c * 8;
  const float* src = X + (long long)row * DIN + k;
  short8 v;
#pragma unroll
  for (int i = 0; i < 8; ++i)
    v[i] = (short)((k + i < DIN) ? f2bf(src[i]) : (unsigned short)0);
  *(short8*)(Xbf + (long long)row * KX + k) = v;
}

// ---------------------------------------------------------------------------
// K1: persistent bidirectional GRU, fused input projection, fence-free sync.
// 128 blocks x 384 thr (6 waves). Group g7 = bid&7 = (dir, batch-chunk of 16);
// 16 blocks/group each own 32 hidden units (ub = bid>>3).
// Per step: x-path MFMAs (pre-wait), slot-flag poll, coherent h loads,
// h-path MFMAs (2 accumulators), gate math fp32, publish h + own slot flag.
// Protocol: data stores are agent-coherent (sc0 sc1, write-through); the
// __syncthreads before the flag store drains vmcnt(0) in every wave, so data
// is device-visible before the flag issues. Flags are per-block slots
// (no RMW serialization), monotone counters. No fences -> weights/Xbf stay
// cached in L1/L2 across all 512 steps.
// ---------------------------------------------------------------------------
__global__ __launch_bounds__(384) void k_gru(
    const unsigned short* __restrict__ Xbf,
    const float* __restrict__ Wih_f, const float* __restrict__ Whh_f,
    const float* __restrict__ bih_f, const float* __restrict__ bhh_f,
    const float* __restrict__ Wih_b, const float* __restrict__ Whh_b,
    const float* __restrict__ bih_b, const float* __restrict__ bhh_b,
    const int*  __restrict__ lens,
    unsigned short* __restrict__ hcat,        // [B][T][1024] bf16
    unsigned int* __restrict__ cnt)           // [8][16] slot flags
{
  const int bid = blockIdx.x;
  const int g7 = bid & 7, ub = bid >> 3;
  const int dir = g7 & 1, bc = g7 >> 1;
  const int b0 = bc * 16, u0 = ub * 32;
  const int tid = threadIdx.x;
  const int wv = tid >> 6, ln = tid & 63, lr = ln & 15, lq = ln >> 4;
  const int gt = wv >> 1, uh = wv & 1;       // gate 0..2, unit-half 0..1

  const float* Wih = dir ? Wih_b : Wih_f;
  const float* Whh = dir ? Whh_b : Whh_f;
  const float* bih = dir ? bih_b : bih_f;
  const float* bhh = dir ? bhh_b : bhh_f;

  __shared__ float ghx_s[96 * 17];   // x-path gh, [local gate row][batch]
  __shared__ float ghh_s[96 * 17];   // h-path gh
  __shared__ float h_s[16 * 32];     // exact fp32 carried state
  __shared__ float bih_s[96], bhh_s[96];
  __shared__ int   lens_s[16];

  for (int i = tid; i < 16 * 32; i += 384) h_s[i] = 0.f;
  if (tid < 96) {
    bih_s[tid] = bih[(tid / 32) * H_ + u0 + (tid % 32)];
    bhh_s[tid] = bhh[(tid / 32) * H_ + u0 + (tid % 32)];
  }
  if (tid < 16) lens_s[tid] = lens[b0 + tid];

  // ---- persistent B-fragments (col = lr = gate row; k = lq*8+i) ----
  const int grow = gt * H_ + u0 + uh * 16 + lr;
  short8 wh[16], wx[10];
  {
    const float* wr = Whh + (long long)grow * H_;
#pragma unroll
    for (int kk = 0; kk < 16; ++kk) {
      const int k = kk * 32 + lq * 8;
      const float4 x0 = *(const float4*)(wr + k);
      const float4 x1 = *(const float4*)(wr + k + 4);
      short8 f;
      f[0] = (short)f2bf(x0.x); f[1] = (short)f2bf(x0.y);
      f[2] = (short)f2bf(x0.z); f[3] = (short)f2bf(x0.w);
      f[4] = (short)f2bf(x1.x); f[5] = (short)f2bf(x1.y);
      f[6] = (short)f2bf(x1.z); f[7] = (short)f2bf(x1.w);
      wh[kk] = f;
    }
    const float* wr2 = Wih + (long long)grow * DIN;
#pragma unroll
    for (int kk = 0; kk < 10; ++kk) {
      const int k = kk * 32 + lq * 8;
      short8 f;
#pragma unroll
      for (int i = 0; i < 8; ++i) {
        const float v = (k + i < DIN) ? wr2[k + i] : 0.f;
        f[i] = (short)f2bf(v);
      }
      wx[kk] = f;
    }
  }
  __syncthreads();

  for (int t = 0; t < T_; ++t) {
    const int te = dir ? (T_ - 1 - t) : t;

    // ---- x-path MFMAs: independent of the inter-block flag ----
    f32x4 accx = (f32x4){0.f, 0.f, 0.f, 0.f};
    {
      const unsigned short* xb = Xbf + ((long long)(b0 + lr) * T_ + te) * KX;
#pragma unroll
      for (int kk = 0; kk < 10; ++kk) {
        const short8 a = *(const short8*)(xb + kk * 32 + lq * 8);
        accx = __builtin_amdgcn_mfma_f32_16x16x32_bf16(a, wx[kk], accx, 0, 0, 0);
      }
    }

    // ---- wait for group step t-1 (slot flags), then coherent h loads ----
    f32x4 acch0 = (f32x4){0.f, 0.f, 0.f, 0.f};
    f32x4 acch1 = (f32x4){0.f, 0.f, 0.f, 0.f};
    if (t > 0) {
      if (tid < 16) {
        while (aload(&cnt[g7 * 16 + tid]) < (unsigned int)t)
          __builtin_amdgcn_s_sleep(1);
      }
      __syncthreads();   // loads below cannot hoist above this

      const int tp = dir ? (te + 1) : (te - 1);
      const unsigned int* hb32 = (const unsigned int*)
          (hcat + ((long long)(b0 + lr) * T_ + tp) * TWOH + dir * H_);
      uint4 harr[16];
#pragma unroll
      for (int kk = 0; kk < 16; ++kk) {
        const unsigned int* p = hb32 + kk * 16 + lq * 4;
        harr[kk].x = aload(p + 0);
        harr[kk].y = aload(p + 1);
        harr[kk].z = aload(p + 2);
        harr[kk].w = aload(p + 3);
      }
#pragma unroll
      for (int kk = 0; kk < 16; ++kk) {
        union { uint4 u; short8 s; } c; c.u = harr[kk];
        if (kk & 1)
          acch1 = __builtin_amdgcn_mfma_f32_16x16x32_bf16(c.s, wh[kk], acch1, 0, 0, 0);
        else
          acch0 = __builtin_amdgcn_mfma_f32_16x16x32_bf16(c.s, wh[kk], acch0, 0, 0, 0);
      }
    }

    // ---- scatter partial gh (D: col=lr -> gate row, row=lq*4+r -> batch) --
    {
      const int lrow = gt * 32 + uh * 16 + lr;
#pragma unroll
      for (int r = 0; r < 4; ++r) {
        ghx_s[lrow * 17 + lq * 4 + r] = accx[r];
        ghh_s[lrow * 17 + lq * 4 + r] = acch0[r] + acch1[r];
      }
    }
    __syncthreads();

    // ---- elementwise: 256 threads x 2 adjacent units (paired for 4B store) -
    if (tid < 256) {
      const int up = (tid & 15) * 2, lb = tid >> 4;
      const int len_b = lens_s[lb];
      const bool valid = te < len_b;
      float outp[2];
#pragma unroll
      for (int j = 0; j < 2; ++j) {
        const int u = up + j;
        const float xr = ghx_s[u * 17 + lb]        + bih_s[u];
        const float xz = ghx_s[(32 + u) * 17 + lb] + bih_s[32 + u];
        const float xn = ghx_s[(64 + u) * 17 + lb] + bih_s[64 + u];
        const float gr = ghh_s[u * 17 + lb]        + bhh_s[u];
        const float gz = ghh_s[(32 + u) * 17 + lb] + bhh_s[32 + u];
        const float gn = ghh_s[(64 + u) * 17 + lb] + bhh_s[64 + u];
        const float h_old = h_s[lb * 32 + u];
        const float rg = 1.f / (1.f + __expf(-(xr + gr)));
        const float zg = 1.f / (1.f + __expf(-(xz + gz)));
        const float ng = tanhf(xn + rg * gn);
        const float hn = (1.f - zg) * ng + zg * h_old;
        const float hc = valid ? hn : h_old;
        h_s[lb * 32 + u] = hc;
        outp[j] = valid ? hc : 0.f;
      }
      unsigned int* dst = (unsigned int*)
          (hcat + ((long long)(b0 + lb) * T_ + te) * TWOH + dir * H_ + u0 + up);
      astore(dst, (unsigned int)f2bf(outp[0]) |
                  ((unsigned int)f2bf(outp[1]) << 16));
    }
    __syncthreads();   // drains vmcnt(0) in every wave -> h device-visible
    if (tid == 0) astore(&cnt[g7 * 16 + ub], (unsigned int)(t + 1));
  }
}

// ---------------------------------------------------------------------------
// K2: scores[b,t] = sum_r u_s[r] * tanh(Hcat[b,t,:] . g2r_W[r,:] + g2r_b[r])
// Block = 64 M-rows x full N=256, K=1024; reduce over r in-register.
// ---------------------------------------------------------------------------
__global__ __launch_bounds__(256) void k_scores(
    const unsigned short* __restrict__ hcat,   // [B*T][1024] bf16
    const float* __restrict__ g2rW,            // [256][1024]
    const float* __restrict__ g2rb,
    const float* __restrict__ us,
    float* __restrict__ scores)
{
  const int m0 = blockIdx.x * 64;
  const int tid = threadIdx.x;
  const int wv = tid >> 6, ln = tid & 63, lr = ln & 15, lq = ln >> 4;

  __shared__ unsigned short As[64 * 40];
  __shared__ unsigned short Bs[256 * 40];

  f32x4 acc[16];
#pragma unroll
  for (int j = 0; j < 16; ++j) acc[j] = (f32x4){0.f, 0.f, 0.f, 0.f};

  for (int kt = 0; kt < 32; ++kt) {
    const int k0 = kt * 32;
    __syncthreads();
#pragma unroll
    for (int h = 0; h < 2; ++h) {            // A: 64 rows x 32 bf16
      const int id = tid * 2 + h;
      const int row = id >> 3, kq = id & 7;
      *(uint2*)&As[row * 40 + kq * 4] =
          *(const uint2*)(hcat + (long long)(m0 + row) * TWOH + k0 + kq * 4);
    }
    {
      const float* src = g2rW + (long long)tid * TWOH + k0;
#pragma unroll
      for (int h = 0; h < 4; ++h) {          // B row = tid: 32 floats -> bf16
        const float4 v0 = *(const float4*)(src + h * 8);
        const float4 v1 = *(const float4*)(src + h * 8 + 4);
        short8 f;
        f[0] = (short)f2bf(v0.x); f[1] = (short)f2bf(v0.y);
        f[2] = (short)f2bf(v0.z); f[3] = (short)f2bf(v0.w);
        f[4] = (short)f2bf(v1.x); f[5] = (short)f2bf(v1.y);
        f[6] = (short)f2bf(v1.z); f[7] = (short)f2bf(v1.w);
        *(short8*)&Bs[tid * 40 + h * 8] = f;
      }
    }
    __syncthreads();
    const short8 a = *(const short8*)&As[(wv * 16 + lr) * 40 + lq * 8];
#pragma unroll
    for (int j = 0; j < 16; ++j) {
      const short8 b = *(const short8*)&Bs[(j * 16 + lr) * 40 + lq * 8];
      acc[j] = __builtin_amdgcn_mfma_f32_16x16x32_bf16(a, b, acc[j], 0, 0, 0);
    }
  }

  float part[4] = {0.f, 0.f, 0.f, 0.f};
#pragma unroll
  for (int j = 0; j < 16; ++j) {
    const int col = j * 16 + lr;
    const float bias = g2rb[col];
    const float uw = us[col];
#pragma unroll
    for (int r = 0; r < 4; ++r) part[r] += tanhf(acc[j][r] + bias) * uw;
  }
#pragma unroll
  for (int d = 1; d < 16; d <<= 1) {
#pragma unroll
    for (int r = 0; r < 4; ++r) part[r] += __shfl_xor(part[r], d, 64);
  }
  if (lr == 0) {
#pragma unroll
    for (int r = 0; r < 4; ++r) scores[m0 + wv * 16 + lq * 4 + r] = part[r];
  }
}

// ---------------------------------------------------------------------------
// K3: masked softmax over t per batch (block = batch, 512 threads)
// ---------------------------------------------------------------------------
__global__ __launch_bounds__(512) void k_softmax(
    const float* __restrict__ scores, const int* __restrict__ lens,
    float* __restrict__ wout)
{
  const int b = blockIdx.x;
  const int tid = threadIdx.x, ln = tid & 63, wid = tid >> 6;
  __shared__ float red[8];
  __shared__ float bcast;

  float s = scores[b * T_ + tid];
  if (tid >= lens[b]) s = -1e30f;

  float m = s;
#pragma unroll
  for (int d = 32; d; d >>= 1) m = fmaxf(m, __shfl_xor(m, d, 64));
  if (!ln) red[wid] = m;
  __syncthreads();
  if (tid == 0) {
    float mm = red[0];
#pragma unroll
    for (int i = 1; i < 8; ++i) mm = fmaxf(mm, red[i]);
    bcast = mm;
  }
  __syncthreads();
  const float mx = bcast;

  float e = __expf(s - mx);
  float sum = e;
#pragma unroll
  for (int d = 32; d; d >>= 1) sum += __shfl_xor(sum, d, 64);
  __syncthreads();
  if (!ln) red[wid] = sum;
  __syncthreads();
  if (tid == 0) {
    float ss = 0.f;
#pragma unroll
    for (int i = 0; i < 8; ++i) ss += red[i];
    bcast = ss;
  }
  __syncthreads();
  wout[b * T_ + tid] = e / bcast;
}

// ---------------------------------------------------------------------------
// K4: pooled[b][h] += sum_t w[b,t] * Hcat[b,t,h]   (block = (b, t-chunk 128))
// ---------------------------------------------------------------------------
__global__ __launch_bounds__(256) void k_pool(
    const unsigned short* __restrict__ hcat, const float* __restrict__ wsm,
    float* __restrict__ pooled)
{
  const int b = blockIdx.x >> 2, tc = blockIdx.x & 3;
  const int t0 = tc * 128;
  const int tid = threadIdx.x;
  __shared__ float w_s[128];
  if (tid < 128) w_s[tid] = wsm[b * T_ + t0 + tid];
  __syncthreads();
#pragma unroll
  for (int hc = 0; hc < 4; ++hc) {
    const int h = hc * 256 + tid;
    float acc = 0.f;
    for (int tt = 0; tt < 128; ++tt)
      acc += w_s[tt] * bf2f(hcat[((long long)b * T_ + t0 + tt) * TWOH + h]);
    atomicAdd(&pooled[b * TWOH + h], acc);
  }
}

// ---------------------------------------------------------------------------
// K5: out[b] = sigmoid(pooled[b] . r2o_W + r2o_b)
// ---------------------------------------------------------------------------
__global__ __launch_bounds__(256) void k_out(
    const float* __restrict__ pooled, const float* __restrict__ r2oW,
    const float* __restrict__ r2ob, float* __restrict__ out)
{
  const int b = blockIdx.x;
  const int tid = threadIdx.x, ln = tid & 63, wid = tid >> 6;
  __shared__ float red[4];
  float a = 0.f;
  for (int h = tid; h < TWOH; h += 256) a += pooled[b * TWOH + h] * r2oW[h];
#pragma unroll
  for (int d = 32; d; d >>= 1) a += __shfl_xor(a, d, 64);
  if (!ln) red[wid] = a;
  __syncthreads();
  if (tid == 0) {
    const float s = red[0] + red[1] + red[2] + red[3] + r2ob[0];
    out[b] = 1.f / (1.f + expf(-s));
  }
}

// ---------------------------------------------------------------------------
extern "C" void kernel_launch(void* const* d_in, const int* in_sizes, int n_in,
                              void* d_out, int out_size, void* d_ws, size_t ws_size,
                              hipStream_t stream) {
  const float* X     = (const float*)d_in[0];
  const int*   lens  = (const int*)d_in[1];
  const float* Wih_f = (const float*)d_in[3];
  const float* Whh_f = (const float*)d_in[4];
  const float* bih_f = (const float*)d_in[5];
  const float* bhh_f = (const float*)d_in[6];
  const float* Wih_b = (const float*)d_in[7];
  const float* Whh_b = (const float*)d_in[8];
  const float* bih_b = (const float*)d_in[9];
  const float* bhh_b = (const float*)d_in[10];
  const float* g2rW  = (const float*)d_in[11];
  const float* g2rb  = (const float*)d_in[12];
  const float* us    = (const float*)d_in[13];
  const float* r2oW  = (const float*)d_in[14];
  const float* r2ob  = (const float*)d_in[15];

  // workspace layout (non-overlapping, ~84.5 MiB total)
  char* ws = (char*)d_ws;
  unsigned short* Xbf    = (unsigned short*)(ws + 0LL);         // 20 MiB
  unsigned short* hcat   = (unsigned short*)(ws + 20971520LL);  // 64 MiB
  unsigned int*   cnt    = (unsigned int*)  (ws + 88080384LL);  // 4 KiB used
  float*          scores = (float*)         (ws + 88096768LL);  // 128 KiB
  float*          wsm    = (float*)         (ws + 88227840LL);  // 128 KiB
  float*          pooled = (float*)         (ws + 88358912LL);  // 256 KiB
  if (ws_size < 88621056ULL) return;  // fail cleanly (absmax), don't scribble

  hipMemsetAsync(cnt, 0, 4096, stream);
  hipMemsetAsync(pooled, 0, 262144, stream);

  k_xbf<<<5120, 256, 0, stream>>>(X, Xbf);
  k_gru<<<128, 384, 0, stream>>>(Xbf, Wih_f, Whh_f, bih_f, bhh_f,
                                 Wih_b, Whh_b, bih_b, bhh_b, lens, hcat, cnt);
  k_scores<<<512, 256, 0, stream>>>(hcat, g2rW, g2rb, us, scores);
  k_softmax<<<64, 512, 0, stream>>>(scores, lens, wsm);
  k_pool<<<256, 256, 0, stream>>>(hcat, wsm, pooled);
  k_out<<<64, 256, 0, stream>>>(pooled, r2oW, r2ob, (float*)d_out);
}

// Round 5
// 3222.728 us; speedup vs baseline: 2.2931x; 2.2931x over previous
//
#include <hip/hip_runtime.h>

#define B_   64
#define T_   512
#define DIN  300
#define H_   512
#define G3   1536   // 3*H
#define TWOH 1024
#define R_   256
#define KX   320    // DIN padded to mult of 32
#define SPIN_CAP (1 << 18)   // hang-proof: bail to wrong-result, not to hang

typedef __attribute__((ext_vector_type(8))) short short8;
typedef __attribute__((ext_vector_type(4))) float f32x4;

__device__ __forceinline__ unsigned short f2bf(float f) {
  union { float f; unsigned int u; } v; v.f = f;
  unsigned int u = v.u;
  u += 0x7fffu + ((u >> 16) & 1u);   // RTN
  return (unsigned short)(u >> 16);
}
__device__ __forceinline__ float bf2f(unsigned short h) {
  union { unsigned int u; float f; } v; v.u = ((unsigned int)h) << 16;
  return v.f;
}
// LLC-coherent (cross-XCD) relaxed accesses — placement probe + slow path.
__device__ __forceinline__ unsigned int aload(const unsigned int* p) {
  return __hip_atomic_load((unsigned int*)p, __ATOMIC_RELAXED,
                           __HIP_MEMORY_SCOPE_AGENT);
}
__device__ __forceinline__ void astore(unsigned int* p, unsigned int v) {
  __hip_atomic_store(p, v, __ATOMIC_RELAXED, __HIP_MEMORY_SCOPE_AGENT);
}
__device__ __forceinline__ int get_xcc() {
  int x;
  asm volatile("s_getreg_b32 %0, hwreg(HW_REG_XCC_ID)" : "=s"(x));
  return x & 7;
}
// flag load: sc0 = bypass L1 (read shared XCD L2); +sc1 = bypass L2 (read LLC)
__device__ __forceinline__ unsigned int flag_ld(const unsigned int* p, bool fast) {
  unsigned int r;
  if (fast)
    asm volatile("global_load_dword %0, %1, off sc0\n\ts_waitcnt vmcnt(0)"
                 : "=v"(r) : "v"(p) : "memory");
  else
    asm volatile("global_load_dword %0, %1, off sc0 sc1\n\ts_waitcnt vmcnt(0)"
                 : "=v"(r) : "v"(p) : "memory");
  return r;
}
__device__ __forceinline__ void flag_st(unsigned int* p, unsigned int v, bool fast) {
  if (fast)   // plain store: L1 is write-through -> lands in shared XCD L2
    asm volatile("global_store_dword %0, %1, off" :: "v"(p), "v"(v) : "memory");
  else        // write-through past L2 so remote XCDs see it at the LLC
    asm volatile("global_store_dword %0, %1, off sc0 sc1" :: "v"(p), "v"(v) : "memory");
}
__device__ __forceinline__ void h_st(unsigned int* p, unsigned int v, bool fast) {
  if (fast)
    asm volatile("global_store_dword %0, %1, off" :: "v"(p), "v"(v) : "memory");
  else
    asm volatile("global_store_dword %0, %1, off sc0 sc1" :: "v"(p), "v"(v) : "memory");
}

// 16 x b128 h-loads, issued back-to-back, single vmcnt(0) inside the asm
// block (defs complete before any consumer -> no waitcnt-hoist hazard).
#define LD16_BODY(CC)                                          \
    "global_load_dwordx4 %0, %16, off " CC "\n\t"              \
    "global_load_dwordx4 %1, %16, off offset:64 " CC "\n\t"    \
    "global_load_dwordx4 %2, %16, off offset:128 " CC "\n\t"   \
    "global_load_dwordx4 %3, %16, off offset:192 " CC "\n\t"   \
    "global_load_dwordx4 %4, %16, off offset:256 " CC "\n\t"   \
    "global_load_dwordx4 %5, %16, off offset:320 " CC "\n\t"   \
    "global_load_dwordx4 %6, %16, off offset:384 " CC "\n\t"   \
    "global_load_dwordx4 %7, %16, off offset:448 " CC "\n\t"   \
    "global_load_dwordx4 %8, %16, off offset:512 " CC "\n\t"   \
    "global_load_dwordx4 %9, %16, off offset:576 " CC "\n\t"   \
    "global_load_dwordx4 %10, %16, off offset:640 " CC "\n\t"  \
    "global_load_dwordx4 %11, %16, off offset:704 " CC "\n\t"  \
    "global_load_dwordx4 %12, %16, off offset:768 " CC "\n\t"  \
    "global_load_dwordx4 %13, %16, off offset:832 " CC "\n\t"  \
    "global_load_dwordx4 %14, %16, off offset:896 " CC "\n\t"  \
    "global_load_dwordx4 %15, %16, off offset:960 " CC "\n\t"  \
    "s_waitcnt vmcnt(0)"
#define LD16_OUTS                                              \
      "=v"(hv[0]), "=v"(hv[1]), "=v"(hv[2]), "=v"(hv[3]),      \
      "=v"(hv[4]), "=v"(hv[5]), "=v"(hv[6]), "=v"(hv[7]),      \
      "=v"(hv[8]), "=v"(hv[9]), "=v"(hv[10]), "=v"(hv[11]),    \
      "=v"(hv[12]), "=v"(hv[13]), "=v"(hv[14]), "=v"(hv[15])

__device__ __forceinline__ void h_ld16(const unsigned int* p, uint4 hv[16], bool fast) {
  if (fast)
    asm volatile(LD16_BODY("sc0") : LD16_OUTS : "v"(p) : "memory");
  else
    asm volatile(LD16_BODY("sc0 sc1") : LD16_OUTS : "v"(p) : "memory");
}

// ---------------------------------------------------------------------------
// K0: X fp32 [B,T,300] -> Xbf bf16 [B,T,320] (zero-padded cols 300..319)
// ---------------------------------------------------------------------------
__global__ __launch_bounds__(256) void k_xbf(
    const float* __restrict__ X, unsigned short* __restrict__ Xbf)
{
  const int id = blockIdx.x * 256 + threadIdx.x;      // B*T*40 items
  if (id >= B_ * T_ * 40) return;
  const int row = id / 40, c = id % 40, k = c * 8;
  const float* src = X + (long long)row * DIN + k;
  short8 v;
#pragma unroll
  for (int i = 0; i < 8; ++i)
    v[i] = (short)((k + i < DIN) ? f2bf(src[i]) : (unsigned short)0);
  *(short8*)(Xbf + (long long)row * KX + k) = v;
}

// ---------------------------------------------------------------------------
// K1: persistent bidirectional GRU, fused input projection, XCD-local sync.
// 128 blocks x 384 thr. Group g7 = bid&7 (= XCD id under round-robin
// dispatch) = (dir, batch-chunk of 16); 16 blocks/group own 32 units each.
// Placement probe (per launch): every block publishes its HW XCC_ID; if all
// 16 group members share one XCD, h/flag traffic uses plain stores + sc0
// loads through the SHARED XCD L2 (coherence point = L2). Otherwise falls
// back to sc0 sc1 (LLC) accesses, which are device-coherent.
// All spins are BOUNDED (SPIN_CAP): a broken protocol produces a wrong
// result (absmax fail, diagnosable) instead of a GPU hang.
// ---------------------------------------------------------------------------
__global__ __launch_bounds__(384) void k_gru(
    const unsigned short* __restrict__ Xbf,
    const float* __restrict__ Wih_f, const float* __restrict__ Whh_f,
    const float* __restrict__ bih_f, const float* __restrict__ bhh_f,
    const float* __restrict__ Wih_b, const float* __restrict__ Whh_b,
    const float* __restrict__ bih_b, const float* __restrict__ bhh_b,
    const int*  __restrict__ lens,
    unsigned short* __restrict__ hcat,        // [B][T][1024] bf16
    unsigned int* __restrict__ cnt)           // [0..127] flags, [128..255] xcds
{
  const int bid = blockIdx.x;
  const int g7 = bid & 7, ub = bid >> 3;
  const int dir = g7 & 1, bc = g7 >> 1;
  const int b0 = bc * 16, u0 = ub * 32;
  const int tid = threadIdx.x;
  const int wv = tid >> 6, ln = tid & 63, lr = ln & 15, lq = ln >> 4;
  const int gt = wv >> 1, uh = wv & 1;       // gate 0..2, unit-half 0..1

  const float* Wih = dir ? Wih_b : Wih_f;
  const float* Whh = dir ? Whh_b : Whh_f;
  const float* bih = dir ? bih_b : bih_f;
  const float* bhh = dir ? bhh_b : bhh_f;

  unsigned int* flags = cnt;           // [8][16]
  unsigned int* xcds  = cnt + 128;     // [128]

  __shared__ float ghx_s[96 * 17];   // x-path gh, [local gate row][batch]
  __shared__ float ghh_s[96 * 17];   // h-path gh
  __shared__ float h_s[16 * 32];     // exact fp32 carried state
  __shared__ float bih_s[96], bhh_s[96];
  __shared__ int   lens_s[16];
  __shared__ int   fast_s;

  for (int i = tid; i < 16 * 32; i += 384) h_s[i] = 0.f;
  if (tid < 96) {
    bih_s[tid] = bih[(tid / 32) * H_ + u0 + (tid % 32)];
    bhh_s[tid] = bhh[(tid / 32) * H_ + u0 + (tid % 32)];
  }
  if (tid < 16) lens_s[tid] = lens[b0 + tid];

  // ---- placement probe (runs every launch; graph-replay safe) ----
  const int xcc = get_xcc();
  if (tid == 0) astore(&xcds[bid], 0x100u | (unsigned int)xcc);
  if (wv == 0) {
    bool match = true;
    if (ln < 16) {
      unsigned int v = 0;
      for (int spin = 0; spin < SPIN_CAP; ++spin) {
        v = aload(&xcds[g7 + ln * 8]);
        if (v >= 0x100u) break;
        __builtin_amdgcn_s_sleep(1);
      }
      // unresolved probe (v<0x100) -> treat as mismatch -> safe slow path
      match = (v >= 0x100u) && ((int)(v & 0xffu) == xcc);
    }
    const int ok = __all(match);
    if (ln == 0) fast_s = ok;
  }

  // ---- persistent B-fragments (col = lr = gate row; k = lq*8+i) ----
  const int grow = gt * H_ + u0 + uh * 16 + lr;
  short8 wh[16], wx[10];
  {
    const float* wr = Whh + (long long)grow * H_;
#pragma unroll
    for (int kk = 0; kk < 16; ++kk) {
      const int k = kk * 32 + lq * 8;
      const float4 x0 = *(const float4*)(wr + k);
      const float4 x1 = *(const float4*)(wr + k + 4);
      short8 f;
      f[0] = (short)f2bf(x0.x); f[1] = (short)f2bf(x0.y);
      f[2] = (short)f2bf(x0.z); f[3] = (short)f2bf(x0.w);
      f[4] = (short)f2bf(x1.x); f[5] = (short)f2bf(x1.y);
      f[6] = (short)f2bf(x1.z); f[7] = (short)f2bf(x1.w);
      wh[kk] = f;
    }
    const float* wr2 = Wih + (long long)grow * DIN;
#pragma unroll
    for (int kk = 0; kk < 10; ++kk) {
      const int k = kk * 32 + lq * 8;
      short8 f;
#pragma unroll
      for (int i = 0; i < 8; ++i) {
        const float v = (k + i < DIN) ? wr2[k + i] : 0.f;
        f[i] = (short)f2bf(v);
      }
      wx[kk] = f;
    }
  }
  __syncthreads();
  const bool fast = fast_s != 0;

  for (int t = 0; t < T_; ++t) {
    const int te = dir ? (T_ - 1 - t) : t;

    // ---- x-path MFMAs: independent of the inter-block flag ----
    f32x4 accx = (f32x4){0.f, 0.f, 0.f, 0.f};
    {
      const unsigned short* xb = Xbf + ((long long)(b0 + lr) * T_ + te) * KX;
#pragma unroll
      for (int kk = 0; kk < 10; ++kk) {
        const short8 a = *(const short8*)(xb + kk * 32 + lq * 8);
        accx = __builtin_amdgcn_mfma_f32_16x16x32_bf16(a, wx[kk], accx, 0, 0, 0);
      }
    }

    // ---- wait for group step t-1 (slot flags), then h loads + MFMAs ----
    f32x4 acch0 = (f32x4){0.f, 0.f, 0.f, 0.f};
    f32x4 acch1 = (f32x4){0.f, 0.f, 0.f, 0.f};
    if (t > 0) {
      if (tid < 16) {
        for (int spin = 0; spin < SPIN_CAP; ++spin) {
          if (flag_ld(&flags[g7 * 16 + tid], fast) >= (unsigned int)t) break;
          __builtin_amdgcn_s_sleep(1);
        }
      }
      __syncthreads();   // h loads below cannot start before the poll passed

      const int tp = dir ? (te + 1) : (te - 1);
      const unsigned int* hb32 = (const unsigned int*)
          (hcat + ((long long)(b0 + lr) * T_ + tp) * TWOH + dir * H_) + lq * 4;
      uint4 hv[16];
      h_ld16(hb32, hv, fast);
#pragma unroll
      for (int kk = 0; kk < 16; ++kk) {
        union { uint4 u; short8 s; } c; c.u = hv[kk];
        if (kk & 1)
          acch1 = __builtin_amdgcn_mfma_f32_16x16x32_bf16(c.s, wh[kk], acch1, 0, 0, 0);
        else
          acch0 = __builtin_amdgcn_mfma_f32_16x16x32_bf16(c.s, wh[kk], acch0, 0, 0, 0);
      }
    }

    // ---- scatter partial gh (D: col=lr -> gate row, row=lq*4+r -> batch) --
    {
      const int lrow = gt * 32 + uh * 16 + lr;
#pragma unroll
      for (int r = 0; r < 4; ++r) {
        ghx_s[lrow * 17 + lq * 4 + r] = accx[r];
        ghh_s[lrow * 17 + lq * 4 + r] = acch0[r] + acch1[r];
      }
    }
    __syncthreads();

    // ---- elementwise: 256 threads x 2 adjacent units (4B store) ----
    if (tid < 256) {
      const int up = (tid & 15) * 2, lb = tid >> 4;
      const bool valid = te < lens_s[lb];
      float outp[2];
#pragma unroll
      for (int j = 0; j < 2; ++j) {
        const int u = up + j;
        const float xr = ghx_s[u * 17 + lb]        + bih_s[u];
        const float xz = ghx_s[(32 + u) * 17 + lb] + bih_s[32 + u];
        const float xn = ghx_s[(64 + u) * 17 + lb] + bih_s[64 + u];
        const float gr = ghh_s[u * 17 + lb]        + bhh_s[u];
        const float gz = ghh_s[(32 + u) * 17 + lb] + bhh_s[32 + u];
        const float gn = ghh_s[(64 + u) * 17 + lb] + bhh_s[64 + u];
        const float h_old = h_s[lb * 32 + u];
        const float rg = 1.f / (1.f + __expf(-(xr + gr)));
        const float zg = 1.f / (1.f + __expf(-(xz + gz)));
        const float ng = tanhf(xn + rg * gn);
        const float hn = (1.f - zg) * ng + zg * h_old;
        const float hc = valid ? hn : h_old;
        h_s[lb * 32 + u] = hc;
        outp[j] = valid ? hc : 0.f;
      }
      unsigned int* dst = (unsigned int*)
          (hcat + ((long long)(b0 + lb) * T_ + te) * TWOH + dir * H_ + u0 + up);
      h_st(dst, (unsigned int)f2bf(outp[0]) |
                ((unsigned int)f2bf(outp[1]) << 16), fast);
    }
    // drain ALL vmem (incl. asm stores the compiler doesn't track), then sync
    asm volatile("s_waitcnt vmcnt(0)" ::: "memory");
    __syncthreads();
    if (tid == 0) flag_st(&flags[g7 * 16 + ub], (unsigned int)(t + 1), fast);
  }
}

// ---------------------------------------------------------------------------
// K2: scores[b,t] = sum_r u_s[r] * tanh(Hcat[b,t,:] . g2r_W[r,:] + g2r_b[r])
// Block = 64 M-rows x full N=256, K=1024; reduce over r in-register.
// ---------------------------------------------------------------------------
__global__ __launch_bounds__(256) void k_scores(
    const unsigned short* __restrict__ hcat,   // [B*T][1024] bf16
    const float* __restrict__ g2rW,            // [256][1024]
    const float* __restrict__ g2rb,
    const float* __restrict__ us,
    float* __restrict__ scores)
{
  const int m0 = blockIdx.x * 64;
  const int tid = threadIdx.x;
  const int wv = tid >> 6, ln = tid & 63, lr = ln & 15, lq = ln >> 4;

  __shared__ unsigned short As[64 * 40];
  __shared__ unsigned short Bs[256 * 40];

  f32x4 acc[16];
#pragma unroll
  for (int j = 0; j < 16; ++j) acc[j] = (f32x4){0.f, 0.f, 0.f, 0.f};

  for (int kt = 0; kt < 32; ++kt) {
    const int k0 = kt * 32;
    __syncthreads();
#pragma unroll
    for (int h = 0; h < 2; ++h) {            // A: 64 rows x 32 bf16
      const int id = tid * 2 + h;
      const int row = id >> 3, kq = id & 7;
      *(uint2*)&As[row * 40 + kq * 4] =
          *(const uint2*)(hcat + (long long)(m0 + row) * TWOH + k0 + kq * 4);
    }
    {
      const float* src = g2rW + (long long)tid * TWOH + k0;
#pragma unroll
      for (int h = 0; h < 4; ++h) {          // B row = tid: 32 floats -> bf16
        const float4 v0 = *(const float4*)(src + h * 8);
        const float4 v1 = *(const float4*)(src + h * 8 + 4);
        short8 f;
        f[0] = (short)f2bf(v0.x); f[1] = (short)f2bf(v0.y);
        f[2] = (short)f2bf(v0.z); f[3] = (short)f2bf(v0.w);
        f[4] = (short)f2bf(v1.x); f[5] = (short)f2bf(v1.y);
        f[6] = (short)f2bf(v1.z); f[7] = (short)f2bf(v1.w);
        *(short8*)&Bs[tid * 40 + h * 8] = f;
      }
    }
    __syncthreads();
    const short8 a = *(const short8*)&As[(wv * 16 + lr) * 40 + lq * 8];
#pragma unroll
    for (int j = 0; j < 16; ++j) {
      const short8 b = *(const short8*)&Bs[(j * 16 + lr) * 40 + lq * 8];
      acc[j] = __builtin_amdgcn_mfma_f32_16x16x32_bf16(a, b, acc[j], 0, 0, 0);
    }
  }

  float part[4] = {0.f, 0.f, 0.f, 0.f};
#pragma unroll
  for (int j = 0; j < 16; ++j) {
    const int col = j * 16 + lr;
    const float bias = g2rb[col];
    const float uw = us[col];
#pragma unroll
    for (int r = 0; r < 4; ++r) part[r] += tanhf(acc[j][r] + bias) * uw;
  }
#pragma unroll
  for (int d = 1; d < 16; d <<= 1) {
#pragma unroll
    for (int r = 0; r < 4; ++r) part[r] += __shfl_xor(part[r], d, 64);
  }
  if (lr == 0) {
#pragma unroll
    for (int r = 0; r < 4; ++r) scores[m0 + wv * 16 + lq * 4 + r] = part[r];
  }
}

// ---------------------------------------------------------------------------
// K3: masked softmax over t per batch (block = batch, 512 threads)
// ---------------------------------------------------------------------------
__global__ __launch_bounds__(512) void k_softmax(
    const float* __restrict__ scores, const int* __restrict__ lens,
    float* __restrict__ wout)
{
  const int b = blockIdx.x;
  const int tid = threadIdx.x, ln = tid & 63, wid = tid >> 6;
  __shared__ float red[8];
  __shared__ float bcast;

  float s = scores[b * T_ + tid];
  if (tid >= lens[b]) s = -1e30f;

  float m = s;
#pragma unroll
  for (int d = 32; d; d >>= 1) m = fmaxf(m, __shfl_xor(m, d, 64));
  if (!ln) red[wid] = m;
  __syncthreads();
  if (tid == 0) {
    float mm = red[0];
#pragma unroll
    for (int i = 1; i < 8; ++i) mm = fmaxf(mm, red[i]);
    bcast = mm;
  }
  __syncthreads();
  const float mx = bcast;

  float e = __expf(s - mx);
  float sum = e;
#pragma unroll
  for (int d = 32; d; d >>= 1) sum += __shfl_xor(sum, d, 64);
  __syncthreads();
  if (!ln) red[wid] = sum;
  __syncthreads();
  if (tid == 0) {
    float ss = 0.f;
#pragma unroll
    for (int i = 0; i < 8; ++i) ss += red[i];
    bcast = ss;
  }
  __syncthreads();
  wout[b * T_ + tid] = e / bcast;
}

// ---------------------------------------------------------------------------
// K4: pooled[b][h] += sum_t w[b,t] * Hcat[b,t,h]   (block = (b, t-chunk 128))
// ---------------------------------------------------------------------------
__global__ __launch_bounds__(256) void k_pool(
    const unsigned short* __restrict__ hcat, const float* __restrict__ wsm,
    float* __restrict__ pooled)
{
  const int b = blockIdx.x >> 2, tc = blockIdx.x & 3;
  const int t0 = tc * 128;
  const int tid = threadIdx.x;
  __shared__ float w_s[128];
  if (tid < 128) w_s[tid] = wsm[b * T_ + t0 + tid];
  __syncthreads();
#pragma unroll
  for (int hc = 0; hc < 4; ++hc) {
    const int h = hc * 256 + tid;
    float acc = 0.f;
    for (int tt = 0; tt < 128; ++tt)
      acc += w_s[tt] * bf2f(hcat[((long long)b * T_ + t0 + tt) * TWOH + h]);
    atomicAdd(&pooled[b * TWOH + h], acc);
  }
}

// ---------------------------------------------------------------------------
// K5: out[b] = sigmoid(pooled[b] . r2o_W + r2o_b)
// ---------------------------------------------------------------------------
__global__ __launch_bounds__(256) void k_out(
    const float* __restrict__ pooled, const float* __restrict__ r2oW,
    const float* __restrict__ r2ob, float* __restrict__ out)
{
  const int b = blockIdx.x;
  const int tid = threadIdx.x, ln = tid & 63, wid = tid >> 6;
  __shared__ float red[4];
  float a = 0.f;
  for (int h = tid; h < TWOH; h += 256) a += pooled[b * TWOH + h] * r2oW[h];
#pragma unroll
  for (int d = 32; d; d >>= 1) a += __shfl_xor(a, d, 64);
  if (!ln) red[wid] = a;
  __syncthreads();
  if (tid == 0) {
    const float s = red[0] + red[1] + red[2] + red[3] + r2ob[0];
    out[b] = 1.f / (1.f + expf(-s));
  }
}

// ---------------------------------------------------------------------------
extern "C" void kernel_launch(void* const* d_in, const int* in_sizes, int n_in,
                              void* d_out, int out_size, void* d_ws, size_t ws_size,
                              hipStream_t stream) {
  const float* X     = (const float*)d_in[0];
  const int*   lens  = (const int*)d_in[1];
  const float* Wih_f = (const float*)d_in[3];
  const float* Whh_f = (const float*)d_in[4];
  const float* bih_f = (const float*)d_in[5];
  const float* bhh_f = (const float*)d_in[6];
  const float* Wih_b = (const float*)d_in[7];
  const float* Whh_b = (const float*)d_in[8];
  const float* bih_b = (const float*)d_in[9];
  const float* bhh_b = (const float*)d_in[10];
  const float* g2rW  = (const float*)d_in[11];
  const float* g2rb  = (const float*)d_in[12];
  const float* us    = (const float*)d_in[13];
  const float* r2oW  = (const float*)d_in[14];
  const float* r2ob  = (const float*)d_in[15];

  // workspace layout (non-overlapping, ~84.5 MiB total)
  char* ws = (char*)d_ws;
  unsigned short* Xbf    = (unsigned short*)(ws + 0LL);         // 20 MiB
  unsigned short* hcat   = (unsigned short*)(ws + 20971520LL);  // 64 MiB
  unsigned int*   cnt    = (unsigned int*)  (ws + 88080384LL);  // 1 KiB used
  float*          scores = (float*)         (ws + 88096768LL);  // 128 KiB
  float*          wsm    = (float*)         (ws + 88227840LL);  // 128 KiB
  float*          pooled = (float*)         (ws + 88358912LL);  // 256 KiB
  if (ws_size < 88621056ULL) return;  // fail cleanly (absmax), don't scribble

  hipMemsetAsync(cnt, 0, 4096, stream);
  hipMemsetAsync(pooled, 0, 262144, stream);

  k_xbf<<<5120, 256, 0, stream>>>(X, Xbf);
  k_gru<<<128, 384, 0, stream>>>(Xbf, Wih_f, Whh_f, bih_f, bhh_f,
                                 Wih_b, Whh_b, bih_b, bhh_b, lens, hcat, cnt);
  k_scores<<<512, 256, 0, stream>>>(hcat, g2rW, g2rb, us, scores);
  k_softmax<<<64, 512, 0, stream>>>(scores, lens, wsm);
  k_pool<<<256, 256, 0, stream>>>(hcat, wsm, pooled);
  k_out<<<64, 256, 0, stream>>>(pooled, r2oW, r2ob, (float*)d_out);
}